// Round 1
// baseline (251.450 us; speedup 1.0000x reference)
//
#include <hip/hip_runtime.h>
#include <hip/hip_bf16.h>
#include <cstdint>

typedef __bf16 bhalf;
typedef __bf16 bhalf8 __attribute__((ext_vector_type(8)));
typedef float f32x4 __attribute__((ext_vector_type(4)));

enum { EPI_STORE=0, EPI_Z2=1, EPI_SIGMOID=2, EPI_BIAS=3, EPI_ATTN=4, EPI_PV=5, EPI_Y=6 };

// ---------------------------------------------------------------------------
// Unified MFMA GEMM:  out[m, n] = epi( sum_k A[m,k] * Bw[n,k] )
// A: [M, K] bf16 row-major (K-contiguous), Bw: [N, K] bf16 row-major.
// 128x128 tile, BK=32, 4 waves (2x2), 16x16x32 bf16 MFMA.
// LDS stride 40 elems (80B): conflict-free ds_write_b128 / ds_read_b128.
// ---------------------------------------------------------------------------
template<int EPI>
__global__ void __launch_bounds__(256, 2)
gemm_bt(const bhalf* __restrict__ A, const bhalf* __restrict__ Bw,
        void* __restrict__ Out,
        const float* __restrict__ bias,
        const bhalf* __restrict__ auxb,
        const float* __restrict__ auxf,
        int M, int N, int K,
        long sA, long sB, long sO, long sAuxb, long sAuxf,
        float scale)
{
  constexpr int BM=128, BK=32, LSTR=40;
  const int bz = blockIdx.z;
  const bhalf* Ab = A + (long)bz * sA;
  const bhalf* Bb = Bw + (long)bz * sB;
  const int tid = threadIdx.x;
  const int wid = tid >> 6, lane = tid & 63;
  const int lm = lane & 15, kq = lane >> 4;
  const int wr = (wid >> 1) * 64, wc = (wid & 1) * 64;
  const int m0 = blockIdx.y * BM, n0 = blockIdx.x * 128;

  __shared__ __align__(16) bhalf As[BM*LSTR];
  __shared__ __align__(16) bhalf Bs[BM*LSTR];

  const int srow = tid >> 2;       // 0..63
  const int skb  = tid & 3;        // 0..3

  f32x4 acc[4][4];
  #pragma unroll
  for (int i=0;i<4;i++)
    #pragma unroll
    for (int j=0;j<4;j++) acc[i][j] = f32x4{0.f,0.f,0.f,0.f};

  const bhalf* ap0 = Ab + (long)(m0 + srow) * K + skb*8;
  const bhalf* ap1 = Ab + (long)(m0 + srow + 64) * K + skb*8;
  const bhalf* bp0 = Bb + (long)(n0 + srow) * K + skb*8;
  const bhalf* bp1 = Bb + (long)(n0 + srow + 64) * K + skb*8;

  bhalf* wA0 = As + srow*LSTR + skb*8;
  bhalf* wA1 = As + (srow+64)*LSTR + skb*8;
  bhalf* wB0 = Bs + srow*LSTR + skb*8;
  bhalf* wB1 = Bs + (srow+64)*LSTR + skb*8;

  for (int k0 = 0; k0 < K; k0 += BK) {
    uint4 ra0 = *(const uint4*)(ap0 + k0);
    uint4 ra1 = *(const uint4*)(ap1 + k0);
    uint4 rb0 = *(const uint4*)(bp0 + k0);
    uint4 rb1 = *(const uint4*)(bp1 + k0);
    __syncthreads();                      // previous tile fully consumed
    *(uint4*)wA0 = ra0;
    *(uint4*)wA1 = ra1;
    *(uint4*)wB0 = rb0;
    *(uint4*)wB1 = rb1;
    __syncthreads();                      // tile staged
    bhalf8 af[4], bfr[4];
    #pragma unroll
    for (int i=0;i<4;i++) {
      af[i]  = *(const bhalf8*)(As + (wr + i*16 + lm)*LSTR + kq*8);
      bfr[i] = *(const bhalf8*)(Bs + (wc + i*16 + lm)*LSTR + kq*8);
    }
    #pragma unroll
    for (int i=0;i<4;i++)
      #pragma unroll
      for (int j=0;j<4;j++)
        acc[i][j] = __builtin_amdgcn_mfma_f32_16x16x32_bf16(af[i], bfr[j], acc[i][j], 0,0,0);
  }

  const long ob = (long)bz * sO;
  #pragma unroll
  for (int i=0;i<4;i++) {
    #pragma unroll
    for (int j=0;j<4;j++) {
      const int colg = n0 + wc + j*16 + lm;
      #pragma unroll
      for (int r=0;r<4;r++) {
        const int rowg = m0 + wr + i*16 + kq*4 + r;
        float v = acc[i][j][r];
        if constexpr (EPI==EPI_ATTN)    { v *= scale; v = fmaxf(v, 0.f); v = v*v; }
        if constexpr (EPI==EPI_SIGMOID) { v += bias[colg]; v = 1.f/(1.f + __expf(-v)); }
        if constexpr (EPI==EPI_BIAS)    { v += bias[colg]; }
        if constexpr (EPI==EPI_Z2)      { v += (float)auxb[(long)rowg * N + colg]; }
        if constexpr (EPI==EPI_PV) {
          v *= auxf[(long)bz * sAuxf + rowg];                                  // 1/(den+eps)
          v *= (float)auxb[(long)bz * sAuxb + (long)rowg * N + colg];          // u gate
        }
        if constexpr (EPI==EPI_Y) {
          ((float*)Out)[ob + (long)rowg * N + colg] = v + bias[colg];
        } else {
          ((bhalf*)Out)[ob + (long)rowg * N + colg] = (bhalf)v;
        }
      }
    }
  }
  (void)scale; (void)M;
}

// ---------------------------------------------------------------------------
// fp32 -> bf16 weight conversion, 7 segments in one launch
// ---------------------------------------------------------------------------
struct CvtArgs { const float* src[7]; bhalf* dst[7]; int n[7]; };
__global__ void cvt_multi(CvtArgs a) {
  int seg = blockIdx.y;
  int i = (blockIdx.x * 256 + threadIdx.x) * 4;
  if (i >= a.n[seg]) return;
  float4 f = *(const float4*)(a.src[seg] + i);
  bhalf* d = a.dst[seg] + i;
  d[0] = (bhalf)f.x; d[1] = (bhalf)f.y; d[2] = (bhalf)f.z; d[3] = (bhalf)f.w;
}

// ---------------------------------------------------------------------------
// GroupNorm(1, C): partial sums then finalize (per batch over C*N = 1M elems)
// ---------------------------------------------------------------------------
__global__ void gn_part(const float* __restrict__ x, float* __restrict__ ps, float* __restrict__ pss) {
  int b = blockIdx.y;
  const float* xb = x + (long)b * (512 * 2048);
  float s = 0.f, ss = 0.f;
  #pragma unroll
  for (int it = 0; it < 8; it++) {
    int idx = ((it * 128 + blockIdx.x) * 256 + threadIdx.x) * 4;
    float4 f = *(const float4*)(xb + idx);
    s  += f.x + f.y + f.z + f.w;
    ss += f.x*f.x + f.y*f.y + f.z*f.z + f.w*f.w;
  }
  for (int off = 32; off; off >>= 1) { s += __shfl_xor(s, off); ss += __shfl_xor(ss, off); }
  __shared__ float ls[4], lss[4];
  int wid = threadIdx.x >> 6, lane = threadIdx.x & 63;
  if (lane == 0) { ls[wid] = s; lss[wid] = ss; }
  __syncthreads();
  if (threadIdx.x == 0) {
    s = ls[0]+ls[1]+ls[2]+ls[3]; ss = lss[0]+lss[1]+lss[2]+lss[3];
    ps[b*128 + blockIdx.x] = s; pss[b*128 + blockIdx.x] = ss;
  }
}

__global__ void gn_final(const float* __restrict__ ps, const float* __restrict__ pss,
                         float* __restrict__ stats) {
  int b = blockIdx.x;
  float s = ps[b*128 + threadIdx.x], ss = pss[b*128 + threadIdx.x];
  for (int off = 32; off; off >>= 1) { s += __shfl_xor(s, off); ss += __shfl_xor(ss, off); }
  __shared__ float l0[2], l1[2];
  int wid = threadIdx.x >> 6, lane = threadIdx.x & 63;
  if (lane == 0) { l0[wid] = s; l1[wid] = ss; }
  __syncthreads();
  if (threadIdx.x == 0) {
    s = l0[0] + l0[1]; ss = l1[0] + l1[1];
    float mean = s * (1.f/1048576.f);
    float var  = ss * (1.f/1048576.f) - mean*mean;
    stats[b*2] = mean; stats[b*2+1] = rsqrtf(var + 1e-8f);
  }
}

// ---------------------------------------------------------------------------
// normalize + depthwise conv(k=3, pad=1) + transpose to token-major bf16
// x [B,C,N] fp32 -> zT, dwT [B,N,C] bf16.  32x32 tiles, n-halo of 1.
// ---------------------------------------------------------------------------
__global__ void norm_dw_T(const float* __restrict__ x, const float* __restrict__ stats,
                          const float* __restrict__ dw_w,
                          bhalf* __restrict__ zT, bhalf* __restrict__ dwT) {
  int b = blockIdx.z, n0 = blockIdx.x * 32, c0 = blockIdx.y * 32;
  float mean = stats[b*2], rstd = stats[b*2+1];
  __shared__ float zs[32][35];          // [local c][local n window 0..33]
  int tx = threadIdx.x, ty = threadIdx.y;
  #pragma unroll
  for (int r = 0; r < 4; r++) {
    int c = c0 + ty + r*8;
    for (int cc = tx; cc < 34; cc += 32) {
      int n = n0 - 1 + cc;
      float v = 0.f;
      if (n >= 0 && n < 2048) v = (x[((long)b*512 + c)*2048 + n] - mean) * rstd;
      zs[ty + r*8][cc] = v;
    }
  }
  __syncthreads();
  float w0 = dw_w[(c0+tx)*3+0], w1 = dw_w[(c0+tx)*3+1], w2 = dw_w[(c0+tx)*3+2];
  #pragma unroll
  for (int r = 0; r < 4; r++) {
    int ln = ty + r*8;
    float z = zs[tx][ln+1];
    float d = w0*zs[tx][ln] + w1*zs[tx][ln+1] + w2*zs[tx][ln+2];
    long o = ((long)b*2048 + n0 + ln) * 512 + c0 + tx;
    zT[o] = (bhalf)z; dwT[o] = (bhalf)d;
  }
}

// ---------------------------------------------------------------------------
// bf16 transpose: in [b, R, C] -> out [b, C, R]
// ---------------------------------------------------------------------------
__global__ void transpose_bf16(const bhalf* __restrict__ in, bhalf* __restrict__ out,
                               int R, int C) {
  __shared__ bhalf t[32][33];
  int r0 = blockIdx.x * 32, c0 = blockIdx.y * 32;
  long ib = (long)blockIdx.z * R * C;
  int tx = threadIdx.x, ty = threadIdx.y;
  #pragma unroll
  for (int r = 0; r < 4; r++)
    t[ty + r*8][tx] = in[ib + (long)(r0 + ty + r*8) * C + c0 + tx];
  __syncthreads();
  #pragma unroll
  for (int r = 0; r < 4; r++)
    out[ib + (long)(c0 + ty + r*8) * R + r0 + tx] = t[tx][ty + r*8];
}

// ---------------------------------------------------------------------------
// row sums of w [rows, 2048] bf16 -> rden = 1/(sum + eps); one wave per row
// ---------------------------------------------------------------------------
__global__ void rowsum_w(const bhalf* __restrict__ w, float* __restrict__ rden) {
  int row = blockIdx.x * 4 + (threadIdx.x >> 6);
  int lane = threadIdx.x & 63;
  const bhalf* p = w + (long)row * 2048;
  float s = 0.f;
  #pragma unroll
  for (int it = 0; it < 4; it++) {
    uint4 v = *(const uint4*)(p + it*512 + lane*8);
    const uint32_t* q4 = reinterpret_cast<const uint32_t*>(&v);
    #pragma unroll
    for (int j = 0; j < 4; j++) {
      s += __uint_as_float(q4[j] << 16);
      s += __uint_as_float(q4[j] & 0xffff0000u);
    }
  }
  for (int off = 32; off; off >>= 1) s += __shfl_xor(s, off);
  if (lane == 0) rden[row] = 1.f / (s + 1e-8f);
}

// ---------------------------------------------------------------------------
// out[b,c,n] = x[b,c,n] + yT[b,n,c]   (fp32, 32x32 tiled transpose-add)
// ---------------------------------------------------------------------------
__global__ void final_add(const float* __restrict__ x, const float* __restrict__ yT,
                          float* __restrict__ out) {
  __shared__ float t[32][33];
  int n0 = blockIdx.x * 32, c0 = blockIdx.y * 32, b = blockIdx.z;
  int tx = threadIdx.x, ty = threadIdx.y;
  #pragma unroll
  for (int r = 0; r < 4; r++)
    t[ty + r*8][tx] = yT[((long)b*2048 + n0 + ty + r*8) * 512 + c0 + tx];
  __syncthreads();
  #pragma unroll
  for (int r = 0; r < 4; r++) {
    long idx = ((long)b*512 + c0 + ty + r*8) * 2048 + n0 + tx;
    out[idx] = x[idx] + t[tx][ty + r*8];
  }
}

// ---------------------------------------------------------------------------
extern "C" void kernel_launch(void* const* d_in, const int* in_sizes, int n_in,
                              void* d_out, int out_size, void* d_ws, size_t ws_size,
                              hipStream_t stream) {
  (void)in_sizes; (void)n_in; (void)out_size; (void)ws_size;
  const float* x    = (const float*)d_in[0];
  const float* dw_w = (const float*)d_in[1];
  const float* pw_w = (const float*)d_in[2];
  const float* u_w  = (const float*)d_in[3];
  const float* u_b  = (const float*)d_in[4];
  const float* v_w  = (const float*)d_in[5];
  const float* v_b  = (const float*)d_in[6];
  const float* h_w  = (const float*)d_in[7];
  const float* h_b  = (const float*)d_in[8];
  const float* q_w  = (const float*)d_in[9];
  const float* k_w  = (const float*)d_in[10];
  const float* o_w  = (const float*)d_in[11];
  const float* o_b  = (const float*)d_in[12];
  float* out = (float*)d_out;

  char* ws = (char*)d_ws;
  size_t off = 0;
  auto alloc = [&](size_t bytes) -> void* {
    void* p = ws + off; off = (off + bytes + 255) & ~(size_t)255; return p;
  };

  float* ps    = (float*)alloc(4*128*4);
  float* pss   = (float*)alloc(4*128*4);
  float* stats = (float*)alloc(4*2*4);
  bhalf* wb_pw = (bhalf*)alloc(512*512*2);
  bhalf* wb_u  = (bhalf*)alloc(1024*512*2);
  bhalf* wb_v  = (bhalf*)alloc(1024*512*2);
  bhalf* wb_h  = (bhalf*)alloc(512*512*2);
  bhalf* wb_q  = (bhalf*)alloc(512*512*2);
  bhalf* wb_k  = (bhalf*)alloc(512*512*2);
  bhalf* wb_o  = (bhalf*)alloc(512*1024*2);
  const size_t ACT = (size_t)4*2048*512;    // 4.19M elems
  bhalf* zT   = (bhalf*)alloc(ACT*2);       // reused as qb
  bhalf* dwT  = (bhalf*)alloc(ACT*2);       // reused as kb
  bhalf* z2T  = (bhalf*)alloc(ACT*2);
  bhalf* ub   = (bhalf*)alloc(ACT*2*2);     // [B,N,1024]
  bhalf* vT   = (bhalf*)alloc(ACT*2*2);     // reused as yT (fp32, same bytes)
  bhalf* v_fm = (bhalf*)alloc(ACT*2*2);     // [B,1024,2048]
  bhalf* hb   = (bhalf*)alloc(ACT*2);
  bhalf* wsc  = (bhalf*)alloc((size_t)4*2048*2048*2);  // scores 32MB
  float* rden = (float*)alloc(4*2048*4);
  bhalf* uav  = (bhalf*)alloc(ACT*2*2);
  bhalf* qb = zT;  bhalf* kb = dwT;  float* yT = (float*)vT;

  // 1. weights -> bf16
  CvtArgs ca;
  ca.src[0]=pw_w; ca.dst[0]=wb_pw; ca.n[0]=512*512;
  ca.src[1]=u_w;  ca.dst[1]=wb_u;  ca.n[1]=1024*512;
  ca.src[2]=v_w;  ca.dst[2]=wb_v;  ca.n[2]=1024*512;
  ca.src[3]=h_w;  ca.dst[3]=wb_h;  ca.n[3]=512*512;
  ca.src[4]=q_w;  ca.dst[4]=wb_q;  ca.n[4]=512*512;
  ca.src[5]=k_w;  ca.dst[5]=wb_k;  ca.n[5]=512*512;
  ca.src[6]=o_w;  ca.dst[6]=wb_o;  ca.n[6]=512*1024;
  cvt_multi<<<dim3(512, 7), 256, 0, stream>>>(ca);

  // 2-3. GroupNorm stats
  gn_part<<<dim3(128, 4), 256, 0, stream>>>(x, ps, pss);
  gn_final<<<dim3(4), 128, 0, stream>>>(ps, pss, stats);

  // 4. normalize + dw conv + transpose -> zT, dwT
  norm_dw_T<<<dim3(64, 16, 4), dim3(32, 8), 0, stream>>>(x, stats, dw_w, zT, dwT);

  const float iscl = 0.044194173824159216f;   // 1/sqrt(512)
  // 5. z2 = z + dw @ pw^T
  gemm_bt<EPI_Z2><<<dim3(4, 64, 1), 256, 0, stream>>>(dwT, wb_pw, z2T, nullptr, zT, nullptr,
      8192, 512, 512, 0,0,0,0,0, 0.f);
  // 6. u = sigmoid(z2 @ u_w^T + u_b)
  gemm_bt<EPI_SIGMOID><<<dim3(8, 64, 1), 256, 0, stream>>>(z2T, wb_u, ub, u_b, nullptr, nullptr,
      8192, 1024, 512, 0,0,0,0,0, 0.f);
  // 7. v = z2 @ v_w^T + v_b   (token-major)
  gemm_bt<EPI_BIAS><<<dim3(8, 64, 1), 256, 0, stream>>>(z2T, wb_v, vT, v_b, nullptr, nullptr,
      8192, 1024, 512, 0,0,0,0,0, 0.f);
  // 8. h = z2 @ h_w^T + h_b
  gemm_bt<EPI_BIAS><<<dim3(4, 64, 1), 256, 0, stream>>>(z2T, wb_h, hb, h_b, nullptr, nullptr,
      8192, 512, 512, 0,0,0,0,0, 0.f);
  // 9-10. q, k
  gemm_bt<EPI_STORE><<<dim3(4, 64, 1), 256, 0, stream>>>(hb, wb_q, qb, nullptr, nullptr, nullptr,
      8192, 512, 512, 0,0,0,0,0, 0.f);
  gemm_bt<EPI_STORE><<<dim3(4, 64, 1), 256, 0, stream>>>(hb, wb_k, kb, nullptr, nullptr, nullptr,
      8192, 512, 512, 0,0,0,0,0, 0.f);
  // 11. v -> feature-major [B, 1024, 2048]
  transpose_bf16<<<dim3(64, 32, 4), dim3(32, 8), 0, stream>>>(vT, v_fm, 2048, 1024);
  // 12. scores w = relu(q@k^T * scale)^2   (bf16, per batch)
  gemm_bt<EPI_ATTN><<<dim3(16, 16, 4), 256, 0, stream>>>(qb, kb, wsc, nullptr, nullptr, nullptr,
      2048, 2048, 512, (long)2048*512, (long)2048*512, (long)2048*2048, 0, 0, iscl);
  // 13. rden = 1/(rowsum + eps)
  rowsum_w<<<dim3(2048), 256, 0, stream>>>(wsc, rden);
  // 14. uav = u * (w @ v_fm^T) * rden    [B, N, 1024]
  gemm_bt<EPI_PV><<<dim3(8, 16, 4), 256, 0, stream>>>(wsc, v_fm, uav, nullptr, ub, rden,
      2048, 1024, 2048, (long)2048*2048, (long)1024*2048, (long)2048*1024,
      (long)2048*1024, 2048, 0.f);
  // 15. yT = uav @ o_w^T + o_b   (fp32 token-major)
  gemm_bt<EPI_Y><<<dim3(4, 64, 1), 256, 0, stream>>>(uav, wb_o, yT, o_b, nullptr, nullptr,
      8192, 512, 1024, 0,0,0,0,0, 0.f);
  // 16. out = x + yT^T
  final_add<<<dim3(64, 16, 4), dim3(32, 8), 0, stream>>>(x, yT, out);
}

// Round 2
// 235.385 us; speedup vs baseline: 1.0683x; 1.0683x over previous
//
#include <hip/hip_runtime.h>
#include <hip/hip_bf16.h>
#include <cstdint>

typedef __bf16 bhalf;
typedef __bf16 bhalf8 __attribute__((ext_vector_type(8)));
typedef float f32x4 __attribute__((ext_vector_type(4)));

enum { EPI_Z2=0, EPI_UV=1, EPI_BIAS=2, EPI_QK=3, EPI_ATTN=4, EPI_PV=5, EPI_Y=6 };

// async global->LDS, 16B per lane, LDS dest = wave-uniform base + lane*16
__device__ __forceinline__ void gl_lds16(const bhalf* g, bhalf* l) {
  __builtin_amdgcn_global_load_lds(
      (const __attribute__((address_space(1))) unsigned int*)g,
      (__attribute__((address_space(3))) unsigned int*)l,
      16, 0, 0);
}

// ---------------------------------------------------------------------------
// Unified MFMA GEMM (m97 structure):  out[m,n] = epi( sum_k A[m,k] * Bw[n,k] )
// A: [M,K] bf16 row-major, Bw: [N,K] bf16 row-major. 128x128 tile, BK=32,
// 4 waves (2x2), 16x16x32 bf16 MFMA, linear LDS [128][32], global_load_lds x16,
// XCD-aware bijective block swizzle.
// ---------------------------------------------------------------------------
template<int EPI>
__global__ void __launch_bounds__(256, 2)
gemm_bt(const bhalf* __restrict__ A, const bhalf* __restrict__ Bw,
        void* __restrict__ Out, void* __restrict__ Out2,
        const float* __restrict__ bias, const float* __restrict__ bias2,
        const bhalf* __restrict__ auxb, const float* __restrict__ auxf,
        int M, int N, int K,
        long sA, long sB, long sO, long sAuxb, long sAuxf,
        float scale)
{
  const int bz = blockIdx.z;
  // XCD-aware bijective swizzle within the (x,y) plane (m204 formula)
  const int gx = gridDim.x, gy = gridDim.y;
  const int nwg = gx * gy;
  const int flat = blockIdx.y * gx + blockIdx.x;
  const int q8 = nwg >> 3, r8 = nwg & 7, xcd = flat & 7, o8 = flat >> 3;
  const int w = (xcd < r8 ? xcd * (q8 + 1) : r8 * (q8 + 1) + (xcd - r8) * q8) + o8;
  const int bx = w % gx, by = w / gx;

  const bhalf* Ab = A + (long)bz * sA;
  const bhalf* Bb = Bw + (long)bz * sB;
  const int tid = threadIdx.x;
  const int wid = tid >> 6, lane = tid & 63;
  const int lm = lane & 15, kq = lane >> 4;
  const int wr = (wid >> 1) * 64, wc = (wid & 1) * 64;
  const int m0 = by * 128, n0 = bx * 128;

  __shared__ __align__(16) bhalf As[128 * 32];
  __shared__ __align__(16) bhalf Bs[128 * 32];

  f32x4 acc[4][4];
  #pragma unroll
  for (int i = 0; i < 4; i++)
    #pragma unroll
    for (int j = 0; j < 4; j++) acc[i][j] = f32x4{0.f, 0.f, 0.f, 0.f};

  // staging: wave w covers rows [wid*32, wid*32+32), 2 chunks of 16 rows each.
  // lane l -> row +(l>>2), col (l&3)*8 ; LDS linear dest matches (row-major [128][32])
  const int l4 = lane >> 2;
  const int lk = (lane & 3) * 8;
  const bhalf* gA0 = Ab + (long)(m0 + wid * 32 + l4) * K + lk;
  const bhalf* gA1 = gA0 + (long)16 * K;
  const bhalf* gB0 = Bb + (long)(n0 + wid * 32 + l4) * K + lk;
  const bhalf* gB1 = gB0 + (long)16 * K;
  bhalf* lA0 = As + (wid * 32) * 32;
  bhalf* lA1 = As + (wid * 32 + 16) * 32;
  bhalf* lB0 = Bs + (wid * 32) * 32;
  bhalf* lB1 = Bs + (wid * 32 + 16) * 32;

  for (int k0 = 0; k0 < K; k0 += 32) {
    __syncthreads();                      // previous tile fully consumed
    gl_lds16(gA0 + k0, lA0);
    gl_lds16(gA1 + k0, lA1);
    gl_lds16(gB0 + k0, lB0);
    gl_lds16(gB1 + k0, lB1);
    __syncthreads();                      // vmcnt(0) drained before barrier
    bhalf8 af[4], bfr[4];
    #pragma unroll
    for (int i = 0; i < 4; i++) {
      af[i]  = *(const bhalf8*)(As + (wr + i * 16 + lm) * 32 + kq * 8);
      bfr[i] = *(const bhalf8*)(Bs + (wc + i * 16 + lm) * 32 + kq * 8);
    }
    #pragma unroll
    for (int i = 0; i < 4; i++)
      #pragma unroll
      for (int j = 0; j < 4; j++)
        acc[i][j] = __builtin_amdgcn_mfma_f32_16x16x32_bf16(af[i], bfr[j], acc[i][j], 0, 0, 0);
  }

  const long ob = (long)bz * sO;
  float rs[4][4];
  if constexpr (EPI == EPI_ATTN) {
    #pragma unroll
    for (int i = 0; i < 4; i++)
      #pragma unroll
      for (int r = 0; r < 4; r++) rs[i][r] = 0.f;
  }
  #pragma unroll
  for (int i = 0; i < 4; i++) {
    #pragma unroll
    for (int j = 0; j < 4; j++) {
      const int colg = n0 + wc + j * 16 + lm;
      #pragma unroll
      for (int r = 0; r < 4; r++) {
        const int rowg = m0 + wr + i * 16 + kq * 4 + r;
        float v = acc[i][j][r];
        if constexpr (EPI == EPI_ATTN) {
          v *= scale; v = fmaxf(v, 0.f); v = v * v;
          rs[i][r] += v;
          ((bhalf*)Out)[ob + (long)rowg * N + colg] = (bhalf)v;
        }
        if constexpr (EPI == EPI_Z2) {
          v += (float)auxb[(long)rowg * N + colg];
          ((bhalf*)Out)[(long)rowg * N + colg] = (bhalf)v;
        }
        if constexpr (EPI == EPI_BIAS) {
          v += bias[colg];
          ((bhalf*)Out)[(long)rowg * N + colg] = (bhalf)v;
        }
        if constexpr (EPI == EPI_UV) {
          if (colg < 1024) {
            v += bias[colg]; v = 1.f / (1.f + __expf(-v));
            ((bhalf*)Out)[(long)rowg * 1024 + colg] = (bhalf)v;
          } else {
            v += bias2[colg - 1024];
            ((bhalf*)Out2)[(long)rowg * 1024 + colg - 1024] = (bhalf)v;
          }
        }
        if constexpr (EPI == EPI_QK) {
          if (colg < 512) ((bhalf*)Out)[(long)rowg * 512 + colg] = (bhalf)v;
          else            ((bhalf*)Out2)[(long)rowg * 512 + colg - 512] = (bhalf)v;
        }
        if constexpr (EPI == EPI_PV) {
          float den = auxf[bz * sAuxf + rowg];
          v *= __builtin_amdgcn_rcpf(den + 1e-8f);
          v *= (float)auxb[(long)bz * sAuxb + (long)rowg * N + colg];
          ((bhalf*)Out)[ob + (long)rowg * N + colg] = (bhalf)v;
        }
        if constexpr (EPI == EPI_Y) {
          ((float*)Out)[(long)rowg * N + colg] = v + bias[colg];
        }
      }
    }
  }
  if constexpr (EPI == EPI_ATTN) {
    float* rden = (float*)Out2;
    #pragma unroll
    for (int i = 0; i < 4; i++) {
      #pragma unroll
      for (int r = 0; r < 4; r++) {
        float s = rs[i][r];
        s += __shfl_xor(s, 1); s += __shfl_xor(s, 2);
        s += __shfl_xor(s, 4); s += __shfl_xor(s, 8);
        if (lm == 0)
          atomicAdd(rden + (long)bz * sAuxf + (m0 + wr + i * 16 + kq * 4 + r), s);
      }
    }
  }
  (void)scale; (void)M; (void)bias2;
}

// ---------------------------------------------------------------------------
// fp32 -> bf16 weight conversion, 7 segments in one launch
// ---------------------------------------------------------------------------
struct CvtArgs { const float* src[7]; bhalf* dst[7]; int n[7]; };
__global__ void cvt_multi(CvtArgs a) {
  int seg = blockIdx.y;
  int i = (blockIdx.x * 256 + threadIdx.x) * 4;
  if (i >= a.n[seg]) return;
  float4 f = *(const float4*)(a.src[seg] + i);
  bhalf* d = a.dst[seg] + i;
  d[0] = (bhalf)f.x; d[1] = (bhalf)f.y; d[2] = (bhalf)f.z; d[3] = (bhalf)f.w;
}

// ---------------------------------------------------------------------------
// GroupNorm(1, C): partial sums then finalize (per batch over C*N = 1M elems)
// ---------------------------------------------------------------------------
__global__ void gn_part(const float* __restrict__ x, float* __restrict__ ps, float* __restrict__ pss) {
  int b = blockIdx.y;
  const float* xb = x + (long)b * (512 * 2048);
  float s = 0.f, ss = 0.f;
  #pragma unroll
  for (int it = 0; it < 8; it++) {
    int idx = ((it * 128 + blockIdx.x) * 256 + threadIdx.x) * 4;
    float4 f = *(const float4*)(xb + idx);
    s  += f.x + f.y + f.z + f.w;
    ss += f.x*f.x + f.y*f.y + f.z*f.z + f.w*f.w;
  }
  for (int off = 32; off; off >>= 1) { s += __shfl_xor(s, off); ss += __shfl_xor(ss, off); }
  __shared__ float ls[4], lss[4];
  int wid = threadIdx.x >> 6, lane = threadIdx.x & 63;
  if (lane == 0) { ls[wid] = s; lss[wid] = ss; }
  __syncthreads();
  if (threadIdx.x == 0) {
    s = ls[0]+ls[1]+ls[2]+ls[3]; ss = lss[0]+lss[1]+lss[2]+lss[3];
    ps[b*128 + blockIdx.x] = s; pss[b*128 + blockIdx.x] = ss;
  }
}

__global__ void gn_final(const float* __restrict__ ps, const float* __restrict__ pss,
                         float* __restrict__ stats) {
  int b = blockIdx.x;
  float s = ps[b*128 + threadIdx.x], ss = pss[b*128 + threadIdx.x];
  for (int off = 32; off; off >>= 1) { s += __shfl_xor(s, off); ss += __shfl_xor(ss, off); }
  __shared__ float l0[2], l1[2];
  int wid = threadIdx.x >> 6, lane = threadIdx.x & 63;
  if (lane == 0) { l0[wid] = s; l1[wid] = ss; }
  __syncthreads();
  if (threadIdx.x == 0) {
    s = l0[0] + l0[1]; ss = l1[0] + l1[1];
    float mean = s * (1.f/1048576.f);
    float var  = ss * (1.f/1048576.f) - mean*mean;
    stats[b*2] = mean; stats[b*2+1] = rsqrtf(var + 1e-8f);
  }
}

// ---------------------------------------------------------------------------
// normalize + depthwise conv(k=3, pad=1) + transpose to token-major bf16
// ---------------------------------------------------------------------------
__global__ void norm_dw_T(const float* __restrict__ x, const float* __restrict__ stats,
                          const float* __restrict__ dw_w,
                          bhalf* __restrict__ zT, bhalf* __restrict__ dwT) {
  int b = blockIdx.z, n0 = blockIdx.x * 32, c0 = blockIdx.y * 32;
  float mean = stats[b*2], rstd = stats[b*2+1];
  __shared__ float zs[32][35];
  int tx = threadIdx.x, ty = threadIdx.y;
  #pragma unroll
  for (int r = 0; r < 4; r++) {
    int c = c0 + ty + r*8;
    for (int cc = tx; cc < 34; cc += 32) {
      int n = n0 - 1 + cc;
      float v = 0.f;
      if (n >= 0 && n < 2048) v = (x[((long)b*512 + c)*2048 + n] - mean) * rstd;
      zs[ty + r*8][cc] = v;
    }
  }
  __syncthreads();
  float w0 = dw_w[(c0+tx)*3+0], w1 = dw_w[(c0+tx)*3+1], w2 = dw_w[(c0+tx)*3+2];
  #pragma unroll
  for (int r = 0; r < 4; r++) {
    int ln = ty + r*8;
    float z = zs[tx][ln+1];
    float d = w0*zs[tx][ln] + w1*zs[tx][ln+1] + w2*zs[tx][ln+2];
    long o = ((long)b*2048 + n0 + ln) * 512 + c0 + tx;
    zT[o] = (bhalf)z; dwT[o] = (bhalf)d;
  }
}

// ---------------------------------------------------------------------------
// bf16 transpose: in [b, R, C] -> out [b, C, R]
// ---------------------------------------------------------------------------
__global__ void transpose_bf16(const bhalf* __restrict__ in, bhalf* __restrict__ out,
                               int R, int C) {
  __shared__ bhalf t[32][33];
  int r0 = blockIdx.x * 32, c0 = blockIdx.y * 32;
  long ib = (long)blockIdx.z * R * C;
  int tx = threadIdx.x, ty = threadIdx.y;
  #pragma unroll
  for (int r = 0; r < 4; r++)
    t[ty + r*8][tx] = in[ib + (long)(r0 + ty + r*8) * C + c0 + tx];
  __syncthreads();
  #pragma unroll
  for (int r = 0; r < 4; r++)
    out[ib + (long)(c0 + ty + r*8) * R + r0 + tx] = t[tx][ty + r*8];
}

// ---------------------------------------------------------------------------
// out[b,c,n] = x[b,c,n] + yT[b,n,c]
// ---------------------------------------------------------------------------
__global__ void final_add(const float* __restrict__ x, const float* __restrict__ yT,
                          float* __restrict__ out) {
  __shared__ float t[32][33];
  int n0 = blockIdx.x * 32, c0 = blockIdx.y * 32, b = blockIdx.z;
  int tx = threadIdx.x, ty = threadIdx.y;
  #pragma unroll
  for (int r = 0; r < 4; r++)
    t[ty + r*8][tx] = yT[((long)b*2048 + n0 + ty + r*8) * 512 + c0 + tx];
  __syncthreads();
  #pragma unroll
  for (int r = 0; r < 4; r++) {
    long idx = ((long)b*512 + c0 + ty + r*8) * 2048 + n0 + tx;
    out[idx] = x[idx] + t[tx][ty + r*8];
  }
}

// ---------------------------------------------------------------------------
extern "C" void kernel_launch(void* const* d_in, const int* in_sizes, int n_in,
                              void* d_out, int out_size, void* d_ws, size_t ws_size,
                              hipStream_t stream) {
  (void)in_sizes; (void)n_in; (void)out_size; (void)ws_size;
  const float* x    = (const float*)d_in[0];
  const float* dw_w = (const float*)d_in[1];
  const float* pw_w = (const float*)d_in[2];
  const float* u_w  = (const float*)d_in[3];
  const float* u_b  = (const float*)d_in[4];
  const float* v_w  = (const float*)d_in[5];
  const float* v_b  = (const float*)d_in[6];
  const float* h_w  = (const float*)d_in[7];
  const float* h_b  = (const float*)d_in[8];
  const float* q_w  = (const float*)d_in[9];
  const float* k_w  = (const float*)d_in[10];
  const float* o_w  = (const float*)d_in[11];
  const float* o_b  = (const float*)d_in[12];
  float* out = (float*)d_out;

  char* ws = (char*)d_ws;
  size_t off = 0;
  auto alloc = [&](size_t bytes) -> void* {
    void* p = ws + off; off = (off + bytes + 255) & ~(size_t)255; return p;
  };

  float* ps    = (float*)alloc(4*128*4);
  float* pss   = (float*)alloc(4*128*4);
  float* stats = (float*)alloc(4*2*4);
  float* rden  = (float*)alloc(4*2048*4);
  bhalf* wb_pw = (bhalf*)alloc(512*512*2);
  bhalf* wb_uv = (bhalf*)alloc((size_t)2048*512*2);
  bhalf* wb_h  = (bhalf*)alloc(512*512*2);
  bhalf* wb_qk = (bhalf*)alloc((size_t)1024*512*2);
  bhalf* wb_o  = (bhalf*)alloc((size_t)512*1024*2);
  const size_t ACT = (size_t)4*2048*512;
  bhalf* zT   = (bhalf*)alloc(ACT*2);       // reused as qb
  bhalf* dwT  = (bhalf*)alloc(ACT*2);       // reused as kb
  bhalf* z2T  = (bhalf*)alloc(ACT*2);
  bhalf* ub   = (bhalf*)alloc(ACT*2*2);     // [B,N,1024]
  bhalf* vT   = (bhalf*)alloc(ACT*2*2);     // reused as yT (fp32)
  bhalf* v_fm = (bhalf*)alloc(ACT*2*2);     // [B,1024,2048]
  bhalf* hb   = (bhalf*)alloc(ACT*2);
  bhalf* wsc  = (bhalf*)alloc((size_t)4*2048*2048*2);
  bhalf* uav  = (bhalf*)alloc(ACT*2*2);
  bhalf* qb = zT;  bhalf* kb = dwT;  float* yT = (float*)vT;

  // 0. zero attention-denominator accumulators (score epilogue atomics)
  hipMemsetAsync(rden, 0, 4*2048*4, stream);

  // 1. weights -> bf16 (u|v and q|k concatenated)
  CvtArgs ca;
  ca.src[0]=pw_w; ca.dst[0]=wb_pw;             ca.n[0]=512*512;
  ca.src[1]=u_w;  ca.dst[1]=wb_uv;             ca.n[1]=1024*512;
  ca.src[2]=v_w;  ca.dst[2]=wb_uv+1024*512;    ca.n[2]=1024*512;
  ca.src[3]=h_w;  ca.dst[3]=wb_h;              ca.n[3]=512*512;
  ca.src[4]=q_w;  ca.dst[4]=wb_qk;             ca.n[4]=512*512;
  ca.src[5]=k_w;  ca.dst[5]=wb_qk+512*512;     ca.n[5]=512*512;
  ca.src[6]=o_w;  ca.dst[6]=wb_o;              ca.n[6]=512*1024;
  cvt_multi<<<dim3(512, 7), 256, 0, stream>>>(ca);

  // 2-3. GroupNorm stats
  gn_part<<<dim3(128, 4), 256, 0, stream>>>(x, ps, pss);
  gn_final<<<dim3(4), 128, 0, stream>>>(ps, pss, stats);

  // 4. normalize + dw conv + transpose -> zT, dwT
  norm_dw_T<<<dim3(64, 16, 4), dim3(32, 8), 0, stream>>>(x, stats, dw_w, zT, dwT);

  const float iscl = 0.044194173824159216f;   // 1/sqrt(512)
  // 5. z2 = z + dw @ pw^T
  gemm_bt<EPI_Z2><<<dim3(4, 64, 1), 256, 0, stream>>>(dwT, wb_pw, z2T, nullptr,
      nullptr, nullptr, zT, nullptr, 8192, 512, 512, 0,0,0,0,0, 0.f);
  // 6. [u|v] = z2 @ [u_w|v_w]^T + b : u sigmoid-gated -> ub, v -> vT
  gemm_bt<EPI_UV><<<dim3(16, 64, 1), 256, 0, stream>>>(z2T, wb_uv, ub, vT,
      u_b, v_b, nullptr, nullptr, 8192, 2048, 512, 0,0,0,0,0, 0.f);
  // 7. h = z2 @ h_w^T + h_b
  gemm_bt<EPI_BIAS><<<dim3(4, 64, 1), 256, 0, stream>>>(z2T, wb_h, hb, nullptr,
      h_b, nullptr, nullptr, nullptr, 8192, 512, 512, 0,0,0,0,0, 0.f);
  // 8. [q|k] = h @ [q_w|k_w]^T
  gemm_bt<EPI_QK><<<dim3(8, 64, 1), 256, 0, stream>>>(hb, wb_qk, qb, kb,
      nullptr, nullptr, nullptr, nullptr, 8192, 1024, 512, 0,0,0,0,0, 0.f);
  // 9. v -> feature-major [B, 1024, 2048]
  transpose_bf16<<<dim3(64, 32, 4), dim3(32, 8), 0, stream>>>(vT, v_fm, 2048, 1024);
  // 10. w = relu(q@k^T * scale)^2 (bf16) + fused row-sum atomics into rden
  gemm_bt<EPI_ATTN><<<dim3(16, 16, 4), 256, 0, stream>>>(qb, kb, wsc, rden,
      nullptr, nullptr, nullptr, nullptr, 2048, 2048, 512,
      (long)2048*512, (long)2048*512, (long)2048*2048, 0, 2048, iscl);
  // 11. uav = u * (w @ v_fm^T) / (den+eps)
  gemm_bt<EPI_PV><<<dim3(8, 16, 4), 256, 0, stream>>>(wsc, v_fm, uav, nullptr,
      nullptr, nullptr, ub, rden, 2048, 1024, 2048,
      (long)2048*2048, (long)1024*2048, (long)2048*1024, (long)2048*1024, 2048, 0.f);
  // 12. yT = uav @ o_w^T + o_b (fp32 token-major)
  gemm_bt<EPI_Y><<<dim3(4, 64, 1), 256, 0, stream>>>(uav, wb_o, yT, nullptr,
      o_b, nullptr, nullptr, nullptr, 8192, 512, 1024, 0,0,0,0,0, 0.f);
  // 13. out = x + yT^T
  final_add<<<dim3(64, 16, 4), dim3(32, 8), 0, stream>>>(x, yT, out);
}